// Round 1
// baseline (2462.005 us; speedup 1.0000x reference)
//
#include <hip/hip_runtime.h>
#include <math.h>

// ============================================================================
// GeometricModule: KNN(20) -> PCA normal/curvature (LAPACK-replica eigh) ->
// local dist feats -> per-point MLP 9->64->128->256, out (B,256,N) f32.
//
// Correctness-critical: eigenvector SIGN must match numpy's ssyevd
// (ssytd2 + ssteqr + sormtr). We replicate that path in f32, fp-contract off.
// LARTG_NEW=1 selects LAPACK >=3.10 slartg (modern OpenBLAS); set 0 for
// the pre-3.10 convention if sign mismatches show up (absmax ~3).
// ============================================================================

#define LARTG_NEW 1
#define NPT 4096
#define KNN 20

// ---------------- LAPACK f32 helper replicas ----------------

__device__ __forceinline__ float slapy2f(float x, float y) {
#pragma clang fp contract(off)
  float xa = fabsf(x), ya = fabsf(y);
  float w = fmaxf(xa, ya);
  float z = fminf(xa, ya);
  if (z == 0.f) return w;
  float q = z / w;
  return w * sqrtf(1.f + q * q);
}

__device__ __forceinline__ void slartgf(float f, float g, float* cs, float* sn, float* rr) {
#pragma clang fp contract(off)
#if LARTG_NEW
  const float safmin = 1.17549435e-38f;
  const float safmax = 8.5070592e37f;
  const float rtmin  = 1.0842022e-19f;   // sqrt(safmin)
  const float rtmax  = 6.5221643e18f;    // sqrt(safmax/2)
  float f1 = fabsf(f), g1 = fabsf(g);
  if (g == 0.f) { *cs = 1.f; *sn = 0.f; *rr = f; }
  else if (f == 0.f) { *cs = 0.f; *sn = copysignf(1.f, g); *rr = g1; }
  else {
    if (f1 > rtmin && f1 < rtmax && g1 > rtmin && g1 < rtmax) {
      float dd = sqrtf(f * f + g * g);
      *cs = f1 / dd;
      float r = copysignf(dd, f);
      *sn = g / r;
      *rr = r;
    } else {
      float u = fminf(safmax, fmaxf(safmin, fmaxf(f1, g1)));
      float fs = f / u, gs = g / u;
      float dd = sqrtf(fs * fs + gs * gs);
      *cs = fabsf(fs) / dd;
      float r = copysignf(dd, f);
      *sn = gs / r;
      *rr = r * u;
    }
  }
#else
  if (g == 0.f) { *cs = 1.f; *sn = 0.f; *rr = f; }
  else if (f == 0.f) { *cs = 0.f; *sn = 1.f; *rr = g; }
  else {
    float r = sqrtf(f * f + g * g);
    float c = f / r, s = g / r;
    if (fabsf(f) > fabsf(g) && c < 0.f) { c = -c; s = -s; r = -r; }
    *cs = c; *sn = s; *rr = r;
  }
#endif
}

__device__ __forceinline__ void slaev2f(float a, float b, float c,
                                        float* rt1, float* rt2, float* cs1, float* sn1) {
#pragma clang fp contract(off)
  float sm = a + c, df = a - c, adf = fabsf(df);
  float tb = b + b, ab = fabsf(tb);
  float acmx, acmn;
  if (fabsf(a) > fabsf(c)) { acmx = a; acmn = c; } else { acmx = c; acmn = a; }
  float rt;
  if (adf > ab)      { float t = ab / adf; rt = adf * sqrtf(1.f + t * t); }
  else if (adf < ab) { float t = adf / ab; rt = ab * sqrtf(1.f + t * t); }
  else               { rt = ab * sqrtf(2.f); }
  int sgn1;
  if (sm < 0.f)      { *rt1 = 0.5f * (sm - rt); sgn1 = -1; *rt2 = (acmx / *rt1) * acmn - (b / *rt1) * b; }
  else if (sm > 0.f) { *rt1 = 0.5f * (sm + rt); sgn1 = 1;  *rt2 = (acmx / *rt1) * acmn - (b / *rt1) * b; }
  else               { *rt1 = 0.5f * rt; *rt2 = -0.5f * rt; sgn1 = 1; }
  float cs; int sgn2;
  if (df >= 0.f) { cs = df + rt; sgn2 = 1; } else { cs = df - rt; sgn2 = -1; }
  float acs = fabsf(cs);
  if (acs > ab) {
    float ct = -tb / cs;
    *sn1 = 1.f / sqrtf(1.f + ct * ct);
    *cs1 = ct * *sn1;
  } else {
    if (ab == 0.f) { *cs1 = 1.f; *sn1 = 0.f; }
    else {
      float tn = -cs / tb;
      *cs1 = 1.f / sqrtf(1.f + tn * tn);
      *sn1 = tn * *cs1;
    }
  }
  if (sgn1 == sgn2) { float tn = *cs1; *cs1 = -*sn1; *sn1 = tn; }
}

// ssyevd path for 3x3 symmetric (lower): ssytd2 -> ssteqr('I') -> sormtr.
// a00,a10,a11,a20,a21,a22 = lower triangle. vec = eigenvector of smallest
// eigenvalue (LAPACK sign), eval = ascending eigenvalues.
__device__ void eig3_lapack(float a00, float a10, float a11, float a20, float a21, float a22,
                            float vec[3], float eval[3]) {
#pragma clang fp contract(off)
  const float eps    = 5.9604645e-08f;
  const float eps2   = 3.5527137e-15f;
  const float safmin = 1.17549435e-38f;
  const float ssfmax = 3.0744573e18f;
  const float ssfmin = 3.0517578e-05f;

  float d[3], e[2], Z[3][3];
  float tau, v2;

  // ---- ssytd2 'L' (one Householder) ----
  {
    float alpha = a10, xx = a20;
    if (xx == 0.f) {
      tau = 0.f; v2 = 0.f;
      e[0] = alpha;
      d[0] = a00; d[1] = a11; d[2] = a22; e[1] = a21;
    } else {
      float xnorm = fabsf(xx);
      float beta = -copysignf(slapy2f(alpha, xnorm), alpha);
      tau = (beta - alpha) / beta;
      float sc = 1.f / (alpha - beta);
      v2 = xx * sc;
      e[0] = beta;
      // x = tau*A22*v (ssymv order), w = x - 0.5*tau*(x.v)*v, rank-2 update
      float x1 = tau * a11 + tau * (a21 * v2);
      float x2 = tau * a21 + (tau * v2) * a22;
      float dotxv = x1 + x2 * v2;
      float aw = (-0.5f * tau) * dotxv;
      float w1 = x1 + aw;
      float w2 = x2 + aw * v2;
      d[0] = a00;
      d[1] = (a11 - w1) - w1;
      e[1] = (a21 - v2 * w1) - w2;
      d[2] = (a22 - v2 * w2) - w2 * v2;
    }
  }
  Z[0][0] = 1.f; Z[0][1] = 0.f; Z[0][2] = 0.f;
  Z[1][0] = 0.f; Z[1][1] = 1.f; Z[1][2] = 0.f;
  Z[2][0] = 0.f; Z[2][1] = 0.f; Z[2][2] = 1.f;

  // ---- ssteqr('I', n=3) faithful transcription (1-based indices) ----
  int nmaxit = 90, jtot = 0, l1 = 1;
  int l = 0, lsv = 0, lend = 0, lendsv = 0, m = 0, iscale = 0;
  float anorm = 0.f, p = 0.f, g = 0.f, r = 0.f, c = 0.f, s = 0.f, rt1 = 0.f, rt2 = 0.f;
  float cw[2], sw[2];
  cw[0] = cw[1] = sw[0] = sw[1] = 0.f;

L10:
  if (l1 > 3) goto L160;
  if (l1 > 1) e[l1 - 2] = 0.f;
  if (l1 <= 2) {
    for (m = l1; m <= 2; ++m) {
      float tst = fabsf(e[m - 1]);
      if (tst == 0.f) goto L30;
      if (tst <= (sqrtf(fabsf(d[m - 1])) * sqrtf(fabsf(d[m]))) * eps) { e[m - 1] = 0.f; goto L30; }
    }
  }
  m = 3;
L30:
  l = l1; lsv = l; lend = m; lendsv = lend; l1 = m + 1;
  if (lend == l) goto L10;
  anorm = fabsf(d[lend - 1]);
  for (int i = l; i < lend; ++i) {
    anorm = fmaxf(anorm, fabsf(d[i - 1]));
    anorm = fmaxf(anorm, fabsf(e[i - 1]));
  }
  iscale = 0;
  if (anorm == 0.f) goto L10;
  if (anorm > ssfmax) {
    iscale = 1;
    float mul = ssfmax / anorm;
    for (int i = l; i <= lend; ++i) d[i - 1] *= mul;
    for (int i = l; i < lend; ++i) e[i - 1] *= mul;
  } else if (anorm < ssfmin) {
    iscale = 2;
    float mul = ssfmin / anorm;
    for (int i = l; i <= lend; ++i) d[i - 1] *= mul;
    for (int i = l; i < lend; ++i) e[i - 1] *= mul;
  }
  if (fabsf(d[lend - 1]) < fabsf(d[l - 1])) { lend = lsv; l = lendsv; }
  if (lend > l) goto L40; else goto L90;

  // ================= QL =================
L40:
  if (l != lend) {
    for (m = l; m <= lend - 1; ++m) {
      float tst = e[m - 1] * e[m - 1];
      if (tst <= (eps2 * fabsf(d[m - 1])) * fabsf(d[m]) + safmin) goto L60;
    }
  }
  m = lend;
L60:
  if (m < lend) e[m - 1] = 0.f;
  p = d[l - 1];
  if (m == l) goto L80;
  if (m == l + 1) {
    slaev2f(d[l - 1], e[l - 1], d[l], &rt1, &rt2, &c, &s);
    for (int i = 0; i < 3; ++i) {
      float t0 = Z[i][l], t1 = Z[i][l - 1];
      Z[i][l]     = c * t0 - s * t1;
      Z[i][l - 1] = s * t0 + c * t1;
    }
    d[l - 1] = rt1; d[l] = rt2; e[l - 1] = 0.f;
    l += 2;
    if (l <= lend) goto L40;
    goto L140;
  }
  if (jtot == nmaxit) goto L140;
  ++jtot;
  g = (d[l] - p) / (2.f * e[l - 1]);
  r = slapy2f(g, 1.f);
  g = d[m - 1] - p + e[l - 1] / (g + copysignf(r, g));
  s = 1.f; c = 1.f; p = 0.f;
  for (int i = m - 1; i >= l; --i) {
    float f = s * e[i - 1];
    float bb = c * e[i - 1];
    slartgf(g, f, &c, &s, &r);
    if (i != m - 1) e[i] = r;
    g = d[i] - p;
    r = (d[i - 1] - g) * s + 2.f * c * bb;
    p = s * r;
    d[i] = g + p;
    g = c * r - bb;
    cw[i - 1] = c; sw[i - 1] = -s;
  }
  {
    int mm = m - l + 1;
    for (int j = mm - 1; j >= 1; --j) {      // SLASR 'R','V','B'
      float ct = cw[l + j - 2], st = sw[l + j - 2];
      int hi = (l - 1) + j;
      for (int i = 0; i < 3; ++i) {
        float t0 = Z[i][hi], t1 = Z[i][hi - 1];
        Z[i][hi]     = ct * t0 - st * t1;
        Z[i][hi - 1] = st * t0 + ct * t1;
      }
    }
  }
  d[l - 1] = d[l - 1] - p;
  e[l - 1] = g;
  goto L40;
L80:
  d[l - 1] = p;
  ++l;
  if (l <= lend) goto L40;
  goto L140;

  // ================= QR =================
L90:
  if (l != lend) {
    for (m = l; m >= lend + 1; --m) {
      float tst = e[m - 2] * e[m - 2];
      if (tst <= (eps2 * fabsf(d[m - 1])) * fabsf(d[m - 2]) + safmin) goto L110;
    }
  }
  m = lend;
L110:
  if (m > lend) e[m - 2] = 0.f;
  p = d[l - 1];
  if (m == l) goto L130;
  if (m == l - 1) {
    slaev2f(d[l - 2], e[l - 2], d[l - 1], &rt1, &rt2, &c, &s);
    for (int i = 0; i < 3; ++i) {            // SLASR 'R','V','F' single rot
      float t0 = Z[i][l - 1], t1 = Z[i][l - 2];
      Z[i][l - 1] = c * t0 - s * t1;
      Z[i][l - 2] = s * t0 + c * t1;
    }
    d[l - 2] = rt1; d[l - 1] = rt2; e[l - 2] = 0.f;
    l -= 2;
    if (l >= lend) goto L90;
    goto L140;
  }
  if (jtot == nmaxit) goto L140;
  ++jtot;
  g = (d[l - 2] - p) / (2.f * e[l - 2]);
  r = slapy2f(g, 1.f);
  g = d[m - 1] - p + e[l - 2] / (g + copysignf(r, g));
  s = 1.f; c = 1.f; p = 0.f;
  for (int i = m; i <= l - 1; ++i) {
    float f = s * e[i - 1];
    float bb = c * e[i - 1];
    slartgf(g, f, &c, &s, &r);
    if (i != m) e[i - 2] = r;
    g = d[i - 1] - p;
    r = (d[i] - g) * s + 2.f * c * bb;
    p = s * r;
    d[i - 1] = g + p;
    g = c * r - bb;
    cw[i - 1] = c; sw[i - 1] = s;
  }
  {
    int mm = l - m + 1;
    for (int j = 1; j <= mm - 1; ++j) {      // SLASR 'R','V','F'
      float ct = cw[m + j - 2], st = sw[m + j - 2];
      int lo = (m - 1) + (j - 1);
      for (int i = 0; i < 3; ++i) {
        float t0 = Z[i][lo + 1], t1 = Z[i][lo];
        Z[i][lo + 1] = ct * t0 - st * t1;
        Z[i][lo]     = st * t0 + ct * t1;
      }
    }
  }
  d[l - 1] = d[l - 1] - p;
  e[l - 2] = g;
  goto L90;
L130:
  d[l - 1] = p;
  --l;
  if (l >= lend) goto L90;
  goto L140;

L140:
  if (iscale == 1) {
    float mul = anorm / ssfmax;
    for (int i = lsv; i <= lendsv; ++i) d[i - 1] *= mul;
    for (int i = lsv; i < lendsv; ++i) e[i - 1] *= mul;
  } else if (iscale == 2) {
    float mul = anorm / ssfmin;
    for (int i = lsv; i <= lendsv; ++i) d[i - 1] *= mul;
    for (int i = lsv; i < lendsv; ++i) e[i - 1] *= mul;
  }
  if (jtot < nmaxit) goto L10;
  goto L160;

L160:
  // selection sort ascending + column swaps (LAPACK ordering)
  for (int ii = 2; ii <= 3; ++ii) {
    int i0 = ii - 1, k = i0;
    float pp = d[i0 - 1];
    for (int j = ii; j <= 3; ++j) {
      if (d[j - 1] < pp) { k = j; pp = d[j - 1]; }
    }
    if (k != i0) {
      d[k - 1] = d[i0 - 1]; d[i0 - 1] = pp;
      for (int rr2 = 0; rr2 < 3; ++rr2) {
        float t = Z[rr2][i0 - 1]; Z[rr2][i0 - 1] = Z[rr2][k - 1]; Z[rr2][k - 1] = t;
      }
    }
  }
  // ---- sormtr: Z := H1 * Z (rows 1,2) ----
  if (tau != 0.f) {
    for (int j = 0; j < 3; ++j) {
      float wj = Z[1][j] + v2 * Z[2][j];
      Z[1][j] = Z[1][j] - tau * wj;
      Z[2][j] = Z[2][j] - (tau * wj) * v2;
    }
  }
  vec[0] = Z[0][0]; vec[1] = Z[1][0]; vec[2] = Z[2][0];
  eval[0] = d[0]; eval[1] = d[1]; eval[2] = d[2];
}

// ---------------- Kernels ----------------

__global__ void prep_kernel(const float* __restrict__ pc, float4* __restrict__ pts4, int total) {
  int i = blockIdx.x * blockDim.x + threadIdx.x;
  if (i < total) {
    float x = pc[i * 3 + 0], y = pc[i * 3 + 1], z = pc[i * 3 + 2];
    pts4[i] = make_float4(x, y, z, fmaf(z, z, fmaf(y, y, x * x)));
  }
}

// One thread per query point. Batch index is uniform per block (blockIdx>>5)
// so candidate loads are scalar (broadcast). Per-thread sorted top-20 in LDS.
__global__ __launch_bounds__(128, 1) void knn_feat_kernel(const float4* __restrict__ pts4,
                                                          float* __restrict__ feat, int total) {
  __shared__ float sd[128 * KNN];
  __shared__ int   si[128 * KNN];
  const int t = threadIdx.x;
  const int b = blockIdx.x >> 5;                 // 32 blocks of 128 per batch
  const int n = ((blockIdx.x & 31) << 7) + t;
  const int p = (b << 12) + n;
  const float4* __restrict__ P = pts4 + ((size_t)b << 12);
  const float4 me = P[n];
  const float xi = me.x, yi = me.y, zi = me.z, sqi = me.w;
  const int base = t * KNN;
#pragma unroll
  for (int k = 0; k < KNN; ++k) sd[base + k] = __builtin_inff();
  float worst = __builtin_inff();
  for (int j = 0; j < NPT; ++j) {
    float4 cj = P[j];                            // uniform -> s_load
    float dot = fmaf(zi, cj.z, fmaf(yi, cj.y, xi * cj.x));
    float d2 = fmaf(-2.f, dot, sqi + cj.w);      // == (sqi+sqj) - 2*dot, one rounding
    if (d2 < worst) {                            // strict <: lower index wins ties (matches top_k)
      int q = KNN - 1;
      while (q > 0 && sd[base + q - 1] > d2) {
        sd[base + q] = sd[base + q - 1];
        si[base + q] = si[base + q - 1];
        --q;
      }
      sd[base + q] = d2;
      si[base + q] = j;
      worst = sd[base + KNN - 1];
    }
  }
  // local distance features (order = ascending d2 = top_k output order)
  float nx[KNN], ny[KNN], nz[KNN];
  float sumd = 0.f, maxd = 0.f;
  float mux = 0.f, muy = 0.f, muz = 0.f;
#pragma unroll
  for (int k = 0; k < KNN; ++k) {
    float d2 = sd[base + k];
    float dist = sqrtf(fmaxf(d2, 0.f) + 1e-12f);
    sumd += dist;
    maxd = fmaxf(maxd, dist);
    float4 nb = P[si[base + k]];
    nx[k] = nb.x; ny[k] = nb.y; nz[k] = nb.z;
    mux += nb.x; muy += nb.y; muz += nb.z;
  }
  float meand = sumd / 20.f;
  mux /= 20.f; muy /= 20.f; muz /= 20.f;
  float cxx = 0.f, cxy = 0.f, cxz = 0.f, cyy = 0.f, cyz = 0.f, czz = 0.f;
#pragma unroll
  for (int k = 0; k < KNN; ++k) {
    float dx = nx[k] - mux, dy = ny[k] - muy, dz = nz[k] - muz;
    cxx = fmaf(dx, dx, cxx); cxy = fmaf(dx, dy, cxy); cxz = fmaf(dx, dz, cxz);
    cyy = fmaf(dy, dy, cyy); cyz = fmaf(dy, dz, cyz); czz = fmaf(dz, dz, czz);
  }
  cxx /= 20.f; cxy /= 20.f; cxz /= 20.f; cyy /= 20.f; cyz /= 20.f; czz /= 20.f;

  float vec[3], ev[3];
  eig3_lapack(cxx, cxy, cyy, cxz, cyz, czz, vec, ev);
  float curv = ev[0] / (((ev[0] + ev[1]) + ev[2]) + 1e-8f);

  feat[0 * total + p] = xi;
  feat[1 * total + p] = yi;
  feat[2 * total + p] = zi;
  feat[3 * total + p] = vec[0];
  feat[4 * total + p] = vec[1];
  feat[5 * total + p] = vec[2];
  feat[6 * total + p] = curv;
  feat[7 * total + p] = meand;
  feat[8 * total + p] = maxd;
}

// Per-point MLP. h1/h2 register-resident (all indexing static via unroll),
// weights uniform -> scalar loads. Stores coalesced per out-channel.
__global__ __launch_bounds__(128, 1) void mlp_kernel(const float* __restrict__ feat,
    const float* __restrict__ W1, const float* __restrict__ B1,
    const float* __restrict__ W2, const float* __restrict__ B2,
    const float* __restrict__ W3, const float* __restrict__ B3,
    float* __restrict__ out, int total) {
  const int t = threadIdx.x;
  const int p = blockIdx.x * 128 + t;
  float f[9];
#pragma unroll
  for (int c = 0; c < 9; ++c) f[c] = feat[c * total + p];
  float h1[64];
#pragma unroll
  for (int o = 0; o < 64; ++o) {
    float acc = B1[o];
#pragma unroll
    for (int i = 0; i < 9; ++i) acc = fmaf(f[i], W1[o * 9 + i], acc);
    h1[o] = fmaxf(acc, 0.f);
  }
  float h2[128];
#pragma unroll
  for (int o = 0; o < 128; ++o) {
    const float* w = W2 + o * 64;
    float a0 = 0.f, a1 = 0.f, a2 = 0.f, a3 = 0.f;
#pragma unroll
    for (int i = 0; i < 64; i += 4) {
      a0 = fmaf(h1[i    ], w[i    ], a0);
      a1 = fmaf(h1[i + 1], w[i + 1], a1);
      a2 = fmaf(h1[i + 2], w[i + 2], a2);
      a3 = fmaf(h1[i + 3], w[i + 3], a3);
    }
    h2[o] = fmaxf(B2[o] + ((a0 + a1) + (a2 + a3)), 0.f);
  }
  const int b = blockIdx.x >> 5;
  const int n = ((blockIdx.x & 31) << 7) + t;
  float* op = out + (size_t)b * 256 * 4096 + n;
  for (int o = 0; o < 256; ++o) {
    const float* w = W3 + o * 128;
    float a0 = 0.f, a1 = 0.f, a2 = 0.f, a3 = 0.f;
#pragma unroll
    for (int i = 0; i < 128; i += 4) {
      a0 = fmaf(h2[i    ], w[i    ], a0);
      a1 = fmaf(h2[i + 1], w[i + 1], a1);
      a2 = fmaf(h2[i + 2], w[i + 2], a2);
      a3 = fmaf(h2[i + 3], w[i + 3], a3);
    }
    op[(size_t)o * 4096] = B3[o] + ((a0 + a1) + (a2 + a3));
  }
}

extern "C" void kernel_launch(void* const* d_in, const int* in_sizes, int n_in,
                              void* d_out, int out_size, void* d_ws, size_t ws_size,
                              hipStream_t stream) {
  const float* pc = (const float*)d_in[0];
  const float* W1 = (const float*)d_in[1];
  const float* b1 = (const float*)d_in[2];
  const float* W2 = (const float*)d_in[3];
  const float* b2 = (const float*)d_in[4];
  const float* W3 = (const float*)d_in[5];
  const float* b3 = (const float*)d_in[6];
  // d_in[7] = vis_mask (all ones) -- unused, matches reference semantics

  const int total = in_sizes[0] / 3;   // B*N = 32768
  float4* pts4 = (float4*)d_ws;
  float* feat = (float*)((char*)d_ws + (size_t)total * sizeof(float4));
  float* outp = (float*)d_out;

  prep_kernel<<<(total + 255) / 256, 256, 0, stream>>>(pc, pts4, total);
  knn_feat_kernel<<<total / 128, 128, 0, stream>>>(pts4, feat, total);
  mlp_kernel<<<total / 128, 128, 0, stream>>>(feat, W1, b1, W2, b2, W3, b3, outp, total);
}

// Round 2
// 1305.061 us; speedup vs baseline: 1.8865x; 1.8865x over previous
//
#include <hip/hip_runtime.h>
#include <math.h>

// ============================================================================
// GeometricModule: KNN(20) -> PCA normal/curvature (LAPACK-replica eigh) ->
// local dist feats -> per-point MLP 9->64->128->256, out (B,256,N) f32.
//
// R2: histogram-threshold KNN (register top-20, branchless insert) +
//     channel-split MLP for occupancy. Eig path unchanged (passed R1).
// ============================================================================

#define LARTG_NEW 1
#define NPT 4096
#define KNN 20
#define CAPS 64   // per-sub-thread collect capacity

// ---------------- LAPACK f32 helper replicas ----------------

__device__ __forceinline__ float slapy2f(float x, float y) {
#pragma clang fp contract(off)
  float xa = fabsf(x), ya = fabsf(y);
  float w = fmaxf(xa, ya);
  float z = fminf(xa, ya);
  if (z == 0.f) return w;
  float q = z / w;
  return w * sqrtf(1.f + q * q);
}

__device__ __forceinline__ void slartgf(float f, float g, float* cs, float* sn, float* rr) {
#pragma clang fp contract(off)
#if LARTG_NEW
  const float safmin = 1.17549435e-38f;
  const float safmax = 8.5070592e37f;
  const float rtmin  = 1.0842022e-19f;
  const float rtmax  = 6.5221643e18f;
  float f1 = fabsf(f), g1 = fabsf(g);
  if (g == 0.f) { *cs = 1.f; *sn = 0.f; *rr = f; }
  else if (f == 0.f) { *cs = 0.f; *sn = copysignf(1.f, g); *rr = g1; }
  else {
    if (f1 > rtmin && f1 < rtmax && g1 > rtmin && g1 < rtmax) {
      float dd = sqrtf(f * f + g * g);
      *cs = f1 / dd;
      float r = copysignf(dd, f);
      *sn = g / r;
      *rr = r;
    } else {
      float u = fminf(safmax, fmaxf(safmin, fmaxf(f1, g1)));
      float fs = f / u, gs = g / u;
      float dd = sqrtf(fs * fs + gs * gs);
      *cs = fabsf(fs) / dd;
      float r = copysignf(dd, f);
      *sn = gs / r;
      *rr = r * u;
    }
  }
#else
  if (g == 0.f) { *cs = 1.f; *sn = 0.f; *rr = f; }
  else if (f == 0.f) { *cs = 0.f; *sn = 1.f; *rr = g; }
  else {
    float r = sqrtf(f * f + g * g);
    float c = f / r, s = g / r;
    if (fabsf(f) > fabsf(g) && c < 0.f) { c = -c; s = -s; r = -r; }
    *cs = c; *sn = s; *rr = r;
  }
#endif
}

__device__ __forceinline__ void slaev2f(float a, float b, float c,
                                        float* rt1, float* rt2, float* cs1, float* sn1) {
#pragma clang fp contract(off)
  float sm = a + c, df = a - c, adf = fabsf(df);
  float tb = b + b, ab = fabsf(tb);
  float acmx, acmn;
  if (fabsf(a) > fabsf(c)) { acmx = a; acmn = c; } else { acmx = c; acmn = a; }
  float rt;
  if (adf > ab)      { float t = ab / adf; rt = adf * sqrtf(1.f + t * t); }
  else if (adf < ab) { float t = adf / ab; rt = ab * sqrtf(1.f + t * t); }
  else               { rt = ab * sqrtf(2.f); }
  int sgn1;
  if (sm < 0.f)      { *rt1 = 0.5f * (sm - rt); sgn1 = -1; *rt2 = (acmx / *rt1) * acmn - (b / *rt1) * b; }
  else if (sm > 0.f) { *rt1 = 0.5f * (sm + rt); sgn1 = 1;  *rt2 = (acmx / *rt1) * acmn - (b / *rt1) * b; }
  else               { *rt1 = 0.5f * rt; *rt2 = -0.5f * rt; sgn1 = 1; }
  float cs; int sgn2;
  if (df >= 0.f) { cs = df + rt; sgn2 = 1; } else { cs = df - rt; sgn2 = -1; }
  float acs = fabsf(cs);
  if (acs > ab) {
    float ct = -tb / cs;
    *sn1 = 1.f / sqrtf(1.f + ct * ct);
    *cs1 = ct * *sn1;
  } else {
    if (ab == 0.f) { *cs1 = 1.f; *sn1 = 0.f; }
    else {
      float tn = -cs / tb;
      *cs1 = 1.f / sqrtf(1.f + tn * tn);
      *sn1 = tn * *cs1;
    }
  }
  if (sgn1 == sgn2) { float tn = *cs1; *cs1 = -*sn1; *sn1 = tn; }
}

__device__ void eig3_lapack(float a00, float a10, float a11, float a20, float a21, float a22,
                            float vec[3], float eval[3]) {
#pragma clang fp contract(off)
  const float eps    = 5.9604645e-08f;
  const float eps2   = 3.5527137e-15f;
  const float safmin = 1.17549435e-38f;
  const float ssfmax = 3.0744573e18f;
  const float ssfmin = 3.0517578e-05f;

  float d[3], e[2], Z[3][3];
  float tau, v2;

  // ---- ssytd2 'L' ----
  {
    float alpha = a10, xx = a20;
    if (xx == 0.f) {
      tau = 0.f; v2 = 0.f;
      e[0] = alpha;
      d[0] = a00; d[1] = a11; d[2] = a22; e[1] = a21;
    } else {
      float xnorm = fabsf(xx);
      float beta = -copysignf(slapy2f(alpha, xnorm), alpha);
      tau = (beta - alpha) / beta;
      float sc = 1.f / (alpha - beta);
      v2 = xx * sc;
      e[0] = beta;
      float x1 = tau * a11 + tau * (a21 * v2);
      float x2 = tau * a21 + (tau * v2) * a22;
      float dotxv = x1 + x2 * v2;
      float aw = (-0.5f * tau) * dotxv;
      float w1 = x1 + aw;
      float w2 = x2 + aw * v2;
      d[0] = a00;
      d[1] = (a11 - w1) - w1;
      e[1] = (a21 - v2 * w1) - w2;
      d[2] = (a22 - v2 * w2) - w2 * v2;
    }
  }
  Z[0][0] = 1.f; Z[0][1] = 0.f; Z[0][2] = 0.f;
  Z[1][0] = 0.f; Z[1][1] = 1.f; Z[1][2] = 0.f;
  Z[2][0] = 0.f; Z[2][1] = 0.f; Z[2][2] = 1.f;

  int nmaxit = 90, jtot = 0, l1 = 1;
  int l = 0, lsv = 0, lend = 0, lendsv = 0, m = 0, iscale = 0;
  float anorm = 0.f, p = 0.f, g = 0.f, r = 0.f, c = 0.f, s = 0.f, rt1 = 0.f, rt2 = 0.f;
  float cw[2], sw[2];
  cw[0] = cw[1] = sw[0] = sw[1] = 0.f;

L10:
  if (l1 > 3) goto L160;
  if (l1 > 1) e[l1 - 2] = 0.f;
  if (l1 <= 2) {
    for (m = l1; m <= 2; ++m) {
      float tst = fabsf(e[m - 1]);
      if (tst == 0.f) goto L30;
      if (tst <= (sqrtf(fabsf(d[m - 1])) * sqrtf(fabsf(d[m]))) * eps) { e[m - 1] = 0.f; goto L30; }
    }
  }
  m = 3;
L30:
  l = l1; lsv = l; lend = m; lendsv = lend; l1 = m + 1;
  if (lend == l) goto L10;
  anorm = fabsf(d[lend - 1]);
  for (int i = l; i < lend; ++i) {
    anorm = fmaxf(anorm, fabsf(d[i - 1]));
    anorm = fmaxf(anorm, fabsf(e[i - 1]));
  }
  iscale = 0;
  if (anorm == 0.f) goto L10;
  if (anorm > ssfmax) {
    iscale = 1;
    float mul = ssfmax / anorm;
    for (int i = l; i <= lend; ++i) d[i - 1] *= mul;
    for (int i = l; i < lend; ++i) e[i - 1] *= mul;
  } else if (anorm < ssfmin) {
    iscale = 2;
    float mul = ssfmin / anorm;
    for (int i = l; i <= lend; ++i) d[i - 1] *= mul;
    for (int i = l; i < lend; ++i) e[i - 1] *= mul;
  }
  if (fabsf(d[lend - 1]) < fabsf(d[l - 1])) { lend = lsv; l = lendsv; }
  if (lend > l) goto L40; else goto L90;

L40:
  if (l != lend) {
    for (m = l; m <= lend - 1; ++m) {
      float tst = e[m - 1] * e[m - 1];
      if (tst <= (eps2 * fabsf(d[m - 1])) * fabsf(d[m]) + safmin) goto L60;
    }
  }
  m = lend;
L60:
  if (m < lend) e[m - 1] = 0.f;
  p = d[l - 1];
  if (m == l) goto L80;
  if (m == l + 1) {
    slaev2f(d[l - 1], e[l - 1], d[l], &rt1, &rt2, &c, &s);
    for (int i = 0; i < 3; ++i) {
      float t0 = Z[i][l], t1 = Z[i][l - 1];
      Z[i][l]     = c * t0 - s * t1;
      Z[i][l - 1] = s * t0 + c * t1;
    }
    d[l - 1] = rt1; d[l] = rt2; e[l - 1] = 0.f;
    l += 2;
    if (l <= lend) goto L40;
    goto L140;
  }
  if (jtot == nmaxit) goto L140;
  ++jtot;
  g = (d[l] - p) / (2.f * e[l - 1]);
  r = slapy2f(g, 1.f);
  g = d[m - 1] - p + e[l - 1] / (g + copysignf(r, g));
  s = 1.f; c = 1.f; p = 0.f;
  for (int i = m - 1; i >= l; --i) {
    float f = s * e[i - 1];
    float bb = c * e[i - 1];
    slartgf(g, f, &c, &s, &r);
    if (i != m - 1) e[i] = r;
    g = d[i] - p;
    r = (d[i - 1] - g) * s + 2.f * c * bb;
    p = s * r;
    d[i] = g + p;
    g = c * r - bb;
    cw[i - 1] = c; sw[i - 1] = -s;
  }
  {
    int mm = m - l + 1;
    for (int j = mm - 1; j >= 1; --j) {
      float ct = cw[l + j - 2], st = sw[l + j - 2];
      int hi = (l - 1) + j;
      for (int i = 0; i < 3; ++i) {
        float t0 = Z[i][hi], t1 = Z[i][hi - 1];
        Z[i][hi]     = ct * t0 - st * t1;
        Z[i][hi - 1] = st * t0 + ct * t1;
      }
    }
  }
  d[l - 1] = d[l - 1] - p;
  e[l - 1] = g;
  goto L40;
L80:
  d[l - 1] = p;
  ++l;
  if (l <= lend) goto L40;
  goto L140;

L90:
  if (l != lend) {
    for (m = l; m >= lend + 1; --m) {
      float tst = e[m - 2] * e[m - 2];
      if (tst <= (eps2 * fabsf(d[m - 1])) * fabsf(d[m - 2]) + safmin) goto L110;
    }
  }
  m = lend;
L110:
  if (m > lend) e[m - 2] = 0.f;
  p = d[l - 1];
  if (m == l) goto L130;
  if (m == l - 1) {
    slaev2f(d[l - 2], e[l - 2], d[l - 1], &rt1, &rt2, &c, &s);
    for (int i = 0; i < 3; ++i) {
      float t0 = Z[i][l - 1], t1 = Z[i][l - 2];
      Z[i][l - 1] = c * t0 - s * t1;
      Z[i][l - 2] = s * t0 + c * t1;
    }
    d[l - 2] = rt1; d[l - 1] = rt2; e[l - 2] = 0.f;
    l -= 2;
    if (l >= lend) goto L90;
    goto L140;
  }
  if (jtot == nmaxit) goto L140;
  ++jtot;
  g = (d[l - 2] - p) / (2.f * e[l - 2]);
  r = slapy2f(g, 1.f);
  g = d[m - 1] - p + e[l - 2] / (g + copysignf(r, g));
  s = 1.f; c = 1.f; p = 0.f;
  for (int i = m; i <= l - 1; ++i) {
    float f = s * e[i - 1];
    float bb = c * e[i - 1];
    slartgf(g, f, &c, &s, &r);
    if (i != m) e[i - 2] = r;
    g = d[i - 1] - p;
    r = (d[i] - g) * s + 2.f * c * bb;
    p = s * r;
    d[i - 1] = g + p;
    g = c * r - bb;
    cw[i - 1] = c; sw[i - 1] = s;
  }
  {
    int mm = l - m + 1;
    for (int j = 1; j <= mm - 1; ++j) {
      float ct = cw[m + j - 2], st = sw[m + j - 2];
      int lo = (m - 1) + (j - 1);
      for (int i = 0; i < 3; ++i) {
        float t0 = Z[i][lo + 1], t1 = Z[i][lo];
        Z[i][lo + 1] = ct * t0 - st * t1;
        Z[i][lo]     = st * t0 + ct * t1;
      }
    }
  }
  d[l - 1] = d[l - 1] - p;
  e[l - 2] = g;
  goto L90;
L130:
  d[l - 1] = p;
  --l;
  if (l >= lend) goto L90;
  goto L140;

L140:
  if (iscale == 1) {
    float mul = anorm / ssfmax;
    for (int i = lsv; i <= lendsv; ++i) d[i - 1] *= mul;
    for (int i = lsv; i < lendsv; ++i) e[i - 1] *= mul;
  } else if (iscale == 2) {
    float mul = anorm / ssfmin;
    for (int i = lsv; i <= lendsv; ++i) d[i - 1] *= mul;
    for (int i = lsv; i < lendsv; ++i) e[i - 1] *= mul;
  }
  if (jtot < nmaxit) goto L10;
  goto L160;

L160:
  for (int ii = 2; ii <= 3; ++ii) {
    int i0 = ii - 1, k = i0;
    float pp = d[i0 - 1];
    for (int j = ii; j <= 3; ++j) {
      if (d[j - 1] < pp) { k = j; pp = d[j - 1]; }
    }
    if (k != i0) {
      d[k - 1] = d[i0 - 1]; d[i0 - 1] = pp;
      for (int rr2 = 0; rr2 < 3; ++rr2) {
        float t = Z[rr2][i0 - 1]; Z[rr2][i0 - 1] = Z[rr2][k - 1]; Z[rr2][k - 1] = t;
      }
    }
  }
  if (tau != 0.f) {
    for (int j = 0; j < 3; ++j) {
      float wj = Z[1][j] + v2 * Z[2][j];
      Z[1][j] = Z[1][j] - tau * wj;
      Z[2][j] = Z[2][j] - (tau * wj) * v2;
    }
  }
  vec[0] = Z[0][0]; vec[1] = Z[1][0]; vec[2] = Z[2][0];
  eval[0] = d[0]; eval[1] = d[1]; eval[2] = d[2];
}

// ---------------- branchless sorted top-20 register insert ----------------
__device__ __forceinline__ void insert20(float d2, int j, float bd[KNN], int bi[KNN]) {
  bool c[KNN];
#pragma unroll
  for (int k = 0; k < KNN; ++k) c[k] = d2 < bd[k];
#pragma unroll
  for (int k = KNN - 1; k >= 1; --k) {
    bd[k] = c[k - 1] ? bd[k - 1] : (c[k] ? d2 : bd[k]);
    bi[k] = c[k - 1] ? bi[k - 1] : (c[k] ? j : bi[k]);
  }
  bd[0] = c[0] ? d2 : bd[0];
  bi[0] = c[0] ? j : bi[0];
}

// ---------------- Kernels ----------------

__global__ void prep_kernel(const float* __restrict__ pc, float4* __restrict__ pts4, int total) {
  int i = blockIdx.x * blockDim.x + threadIdx.x;
  if (i < total) {
    float x = pc[i * 3 + 0], y = pc[i * 3 + 1], z = pc[i * 3 + 2];
    pts4[i] = make_float4(x, y, z, fmaf(z, z, fmaf(y, y, x * x)));
  }
}

// Block: 64 queries x 2 sub-threads. Pass1: per-query exponent histogram
// (ds_add fire-and-forget). Pass2: collect candidates below per-query
// threshold into LDS list. Then wave0 does branchless register top-20,
// PCA/eig, features. Exact-overflow fallback rescans (never on random data).
__global__ __launch_bounds__(128, 2) void knn_feat_kernel(const float4* __restrict__ pts4,
                                                          float* __restrict__ feat, int total) {
  __shared__ int   hist[32][64];
  __shared__ float cbuf[2 * CAPS][64];
  __shared__ int   ibuf[2 * CAPS][64];
  __shared__ int   cnts[2][64];
  __shared__ int   ovfs[2][64];

  const int t = threadIdx.x;
  const int q = t & 63;
  const int s = t >> 6;
  const int b = blockIdx.x >> 6;                  // 64 blocks of 64 queries per batch
  const int n = ((blockIdx.x & 63) << 6) + q;
  const int p = (b << 12) + n;
  const float4* __restrict__ P = pts4 + ((size_t)b << 12);
  const float4 me = P[n];
  const float xi = me.x, yi = me.y, zi = me.z, sqi = me.w;

  {
    int* h = &hist[0][0];
#pragma unroll
    for (int k = 0; k < 16; ++k) h[t * 16 + k] = 0;
  }
  __syncthreads();

  const int j0 = s << 11;                          // 2048 candidates per sub
  // ---- pass 1: exponent-bin histogram ----
#pragma unroll 4
  for (int jj = 0; jj < 2048; ++jj) {
    float4 cj = P[j0 + jj];
    float dot = fmaf(zi, cj.z, fmaf(yi, cj.y, xi * cj.x));
    float d2 = fmaf(-2.f, dot, sqi + cj.w);
    unsigned bits = __float_as_uint(fmaxf(d2, 0.f));
    int bin = (int)(bits >> 23) - 112;
    bin = max(0, min(31, bin));
    atomicAdd(&hist[bin][q], 1);
  }
  __syncthreads();

  // ---- per-query threshold: upper edge of bin where cumcount >= 20 ----
  float thr;
  {
    int cum = 0, T = 0;
#pragma unroll
    for (int k = 0; k < 32; ++k) {
      cum += hist[k][q];
      T = (cum < KNN) ? (k + 1) : T;
    }
    thr = (T >= 31) ? __builtin_inff() : __uint_as_float((unsigned)(113 + T) << 23);
  }

  // ---- pass 2: collect candidates below threshold ----
  int cnt = 0, ov = 0;
#pragma unroll 4
  for (int jj = 0; jj < 2048; ++jj) {
    float4 cj = P[j0 + jj];
    float dot = fmaf(zi, cj.z, fmaf(yi, cj.y, xi * cj.x));
    float d2 = fmaf(-2.f, dot, sqi + cj.w);
    if (d2 < thr) {
      if (cnt < CAPS) {
        cbuf[(s << 6) + cnt][q] = d2;
        ibuf[(s << 6) + cnt][q] = j0 + jj;
        ++cnt;
      } else ov = 1;
    }
  }
  cnts[s][q] = cnt;
  ovfs[s][q] = ov;
  __syncthreads();

  if (s != 0) return;                              // wave 0 finishes the query

  float bd[KNN]; int bi[KNN];
#pragma unroll
  for (int k = 0; k < KNN; ++k) { bd[k] = __builtin_inff(); bi[k] = 0; }

  const int c0 = cnts[0][q], c1 = cnts[1][q];
  int bad = ovfs[0][q] | ovfs[1][q];
  for (int i = 0; i < CAPS; ++i) {
    if (__all(i >= c0)) break;
    if (i < c0) {
      float d2 = cbuf[i][q]; int jj = ibuf[i][q];
      if (d2 < bd[KNN - 1]) insert20(d2, jj, bd, bi);
    }
  }
  for (int i = 0; i < CAPS; ++i) {
    if (__all(i >= c1)) break;
    if (i < c1) {
      float d2 = cbuf[CAPS + i][q]; int jj = ibuf[CAPS + i][q];
      if (d2 < bd[KNN - 1]) insert20(d2, jj, bd, bi);
    }
  }
  // exact fallback on collect overflow (correctness guarantee; ~never taken)
  if (__any(bad)) {
    if (bad) {
#pragma unroll
      for (int k = 0; k < KNN; ++k) { bd[k] = __builtin_inff(); bi[k] = 0; }
    }
    for (int j = 0; j < NPT; ++j) {
      float4 cj = P[j];
      float dot = fmaf(zi, cj.z, fmaf(yi, cj.y, xi * cj.x));
      float d2 = fmaf(-2.f, dot, sqi + cj.w);
      if (bad && d2 < bd[KNN - 1]) insert20(d2, j, bd, bi);
    }
  }

  // ---- distance features + neighbor mean (same arithmetic as R1) ----
  float sumd = 0.f, maxd = 0.f, mux = 0.f, muy = 0.f, muz = 0.f;
#pragma unroll
  for (int k = 0; k < KNN; ++k) {
    float dist = sqrtf(fmaxf(bd[k], 0.f) + 1e-12f);
    sumd += dist;
    maxd = fmaxf(maxd, dist);
    float4 nb = P[bi[k]];
    mux += nb.x; muy += nb.y; muz += nb.z;
  }
  float meand = sumd / 20.f;
  mux /= 20.f; muy /= 20.f; muz /= 20.f;

  float cxx = 0.f, cxy = 0.f, cxz = 0.f, cyy = 0.f, cyz = 0.f, czz = 0.f;
#pragma unroll
  for (int k = 0; k < KNN; ++k) {
    float4 nb = P[bi[k]];                          // L1/L2-hot re-gather
    float dx = nb.x - mux, dy = nb.y - muy, dz = nb.z - muz;
    cxx = fmaf(dx, dx, cxx); cxy = fmaf(dx, dy, cxy); cxz = fmaf(dx, dz, cxz);
    cyy = fmaf(dy, dy, cyy); cyz = fmaf(dy, dz, cyz); czz = fmaf(dz, dz, czz);
  }
  cxx /= 20.f; cxy /= 20.f; cxz /= 20.f; cyy /= 20.f; cyz /= 20.f; czz /= 20.f;

  float vec[3], ev[3];
  eig3_lapack(cxx, cxy, cyy, cxz, cyz, czz, vec, ev);
  float curv = ev[0] / (((ev[0] + ev[1]) + ev[2]) + 1e-8f);

  feat[0 * total + p] = xi;
  feat[1 * total + p] = yi;
  feat[2 * total + p] = zi;
  feat[3 * total + p] = vec[0];
  feat[4 * total + p] = vec[1];
  feat[5 * total + p] = vec[2];
  feat[6 * total + p] = curv;
  feat[7 * total + p] = meand;
  feat[8 * total + p] = maxd;
}

// Block: 4 waves x 64 points. Each wave computes h1/h2 for its lane's point
// (redundant x4, keeps weight addresses wave-uniform -> s_loads) and emits
// its own 64 of the 256 output channels. 2048 waves -> 2 waves/SIMD.
__global__ __launch_bounds__(256, 2) void mlp_kernel(const float* __restrict__ feat,
    const float* __restrict__ W1, const float* __restrict__ B1,
    const float* __restrict__ W2, const float* __restrict__ B2,
    const float* __restrict__ W3, const float* __restrict__ B3,
    float* __restrict__ out, int total) {
  const int t = threadIdx.x;
  const int l = t & 63;
  const int w = t >> 6;                            // output group 0..3
  const int p = blockIdx.x * 64 + l;

  float f[9];
#pragma unroll
  for (int c = 0; c < 9; ++c) f[c] = feat[c * total + p];

  float h1[64];
#pragma unroll
  for (int o = 0; o < 64; ++o) {
    float acc = B1[o];
#pragma unroll
    for (int i = 0; i < 9; ++i) acc = fmaf(f[i], W1[o * 9 + i], acc);
    h1[o] = fmaxf(acc, 0.f);
  }
  float h2[128];
#pragma unroll
  for (int o = 0; o < 128; ++o) {
    const float* wp = W2 + o * 64;
    float a0 = 0.f, a1 = 0.f, a2 = 0.f, a3 = 0.f;
#pragma unroll
    for (int i = 0; i < 64; i += 4) {
      a0 = fmaf(h1[i    ], wp[i    ], a0);
      a1 = fmaf(h1[i + 1], wp[i + 1], a1);
      a2 = fmaf(h1[i + 2], wp[i + 2], a2);
      a3 = fmaf(h1[i + 3], wp[i + 3], a3);
    }
    h2[o] = fmaxf(B2[o] + ((a0 + a1) + (a2 + a3)), 0.f);
  }

  const int b = p >> 12;
  const int n = p & 4095;
  float* op = out + (size_t)b * (256 * 4096) + n;
  const int obase = w << 6;
  for (int oo = 0; oo < 64; ++oo) {
    const int o = obase + oo;                      // wave-uniform row of W3
    const float* wp = W3 + o * 128;
    float a0 = 0.f, a1 = 0.f, a2 = 0.f, a3 = 0.f;
#pragma unroll
    for (int i = 0; i < 128; i += 4) {
      a0 = fmaf(h2[i    ], wp[i    ], a0);
      a1 = fmaf(h2[i + 1], wp[i + 1], a1);
      a2 = fmaf(h2[i + 2], wp[i + 2], a2);
      a3 = fmaf(h2[i + 3], wp[i + 3], a3);
    }
    op[(size_t)o * 4096] = B3[o] + ((a0 + a1) + (a2 + a3));
  }
}

extern "C" void kernel_launch(void* const* d_in, const int* in_sizes, int n_in,
                              void* d_out, int out_size, void* d_ws, size_t ws_size,
                              hipStream_t stream) {
  const float* pc = (const float*)d_in[0];
  const float* W1 = (const float*)d_in[1];
  const float* b1 = (const float*)d_in[2];
  const float* W2 = (const float*)d_in[3];
  const float* b2 = (const float*)d_in[4];
  const float* W3 = (const float*)d_in[5];
  const float* b3 = (const float*)d_in[6];
  // d_in[7] = vis_mask (all ones) -- unused, matches reference semantics

  const int total = in_sizes[0] / 3;               // B*N = 32768
  float4* pts4 = (float4*)d_ws;
  float* feat = (float*)((char*)d_ws + (size_t)total * sizeof(float4));
  float* outp = (float*)d_out;

  prep_kernel<<<(total + 255) / 256, 256, 0, stream>>>(pc, pts4, total);
  knn_feat_kernel<<<total / 64, 128, 0, stream>>>(pts4, feat, total);
  mlp_kernel<<<total / 64, 256, 0, stream>>>(feat, W1, b1, W2, b2, W3, b3, outp, total);
}